// Round 1
// baseline (113.535 us; speedup 1.0000x reference)
//
#include <hip/hip_runtime.h>

#define B_ 2
#define Q_ 2048
#define K_ 2048
#define H_ 16
#define D_ 64

typedef __bf16 bf16_t;
typedef __attribute__((ext_vector_type(8))) __bf16 bf16x8;
typedef __attribute__((ext_vector_type(4))) float f32x4;

__global__ __launch_bounds__(256) void attn_fwd_kernel(
    const float* __restrict__ qs, const float* __restrict__ ks,
    const float* __restrict__ vs, const int* __restrict__ valid_lens,
    float* __restrict__ out)
{
    const int qt   = blockIdx.x;   // q-tile of 64 rows
    const int h    = blockIdx.y;
    const int b    = blockIdx.z;
    const int tid  = threadIdx.x;
    const int wave = tid >> 6;     // 0..3, each owns 16 q rows
    const int lane = tid & 63;
    const int l16  = lane & 15;
    const int lhi  = lane >> 4;    // 0..3

    const int valid  = valid_lens[b];
    const int ntiles = (valid + 31) >> 5;   // tiles fully past valid are exactly zero-weight

    __shared__ bf16_t k_lds[32][64];
    __shared__ bf16_t v_lds[32][64];
    __shared__ bf16_t p_lds[4][16][32];

    // ---- Q fragments (A-layout: lane holds row l16, k = lhi*8+j), scale folded in ----
    const int    qrow = qt * 64 + wave * 16 + l16;
    const float* qp   = qs + (((size_t)b * Q_ + qrow) * H_ + h) * D_;
    bf16x8 a_q[2];
    #pragma unroll
    for (int dh = 0; dh < 2; ++dh) {
        const f32x4* q4 = (const f32x4*)(qp + dh * 32 + lhi * 8);
        f32x4 lo = q4[0], hi = q4[1];
        #pragma unroll
        for (int j = 0; j < 4; ++j) {
            a_q[dh][j]     = (bf16_t)(lo[j] * 0.125f);
            a_q[dh][4 + j] = (bf16_t)(hi[j] * 0.125f);
        }
    }

    f32x4 o_acc[4];
    #pragma unroll
    for (int t = 0; t < 4; ++t) o_acc[t] = (f32x4){0.f, 0.f, 0.f, 0.f};
    float m_r[4], l_r[4];
    #pragma unroll
    for (int r = 0; r < 4; ++r) { m_r[r] = -1e30f; l_r[r] = 0.f; }

    const float* kb = ks + ((size_t)b * K_ * H_ + h) * D_;   // + k*H_*D_
    const float* vg = vs + ((size_t)b * K_ * H_ + h) * D_;

    const int srow = tid >> 3;        // 0..31
    const int scol = (tid & 7) * 8;   // 0..56

    for (int kt = 0; kt < ntiles; ++kt) {
        __syncthreads();   // protect k/v_lds from previous iteration's readers
        {
            const size_t off = (size_t)(kt * 32 + srow) * (H_ * D_) + scol;
            const f32x4* kp = (const f32x4*)(kb + off);
            const f32x4* vp = (const f32x4*)(vg + off);
            f32x4 k0 = kp[0], k1 = kp[1];
            f32x4 v0 = vp[0], v1 = vp[1];
            #pragma unroll
            for (int j = 0; j < 4; ++j) {
                k_lds[srow][scol + j]     = (bf16_t)k0[j];
                k_lds[srow][scol + 4 + j] = (bf16_t)k1[j];
                v_lds[srow][scol + j]     = (bf16_t)v0[j];
                v_lds[srow][scol + 4 + j] = (bf16_t)v1[j];
            }
        }
        __syncthreads();

        // ---- S = (Q*scale) K^T : two 16x16 n-tiles, K-dim 64 in 2 halves ----
        f32x4 s[2];
        s[0] = (f32x4){0.f,0.f,0.f,0.f};
        s[1] = (f32x4){0.f,0.f,0.f,0.f};
        #pragma unroll
        for (int n = 0; n < 2; ++n) {
            #pragma unroll
            for (int dh = 0; dh < 2; ++dh) {
                bf16x8 bk;   // B-layout: lane holds col n*16+l16 (k-index), k-dim d = dh*32+lhi*8+j
                #pragma unroll
                for (int j = 0; j < 8; ++j)
                    bk[j] = k_lds[n * 16 + l16][dh * 32 + lhi * 8 + j];
                s[n] = __builtin_amdgcn_mfma_f32_16x16x32_bf16(a_q[dh], bk, s[n], 0, 0, 0);
            }
        }

        // ---- mask (key padding) ----
        float p[2][4];
        #pragma unroll
        for (int n = 0; n < 2; ++n) {
            const bool ok = (kt * 32 + n * 16 + l16) < valid;
            #pragma unroll
            for (int r = 0; r < 4; ++r)
                p[n][r] = ok ? s[n][r] : -1e30f;
        }

        // ---- online softmax: rows live on 16-lane groups (row = lhi*4 + r) ----
        #pragma unroll
        for (int r = 0; r < 4; ++r) {
            float rm = fmaxf(p[0][r], p[1][r]);
            #pragma unroll
            for (int off = 1; off < 16; off <<= 1)
                rm = fmaxf(rm, __shfl_xor(rm, off, 64));
            const float mnew  = fmaxf(m_r[r], rm);
            const float alpha = __expf(m_r[r] - mnew);
            float psum = 0.f;
            #pragma unroll
            for (int n = 0; n < 2; ++n) {
                const float e = __expf(p[n][r] - mnew);
                p[n][r] = e;
                psum += e;
            }
            #pragma unroll
            for (int off = 1; off < 16; off <<= 1)
                psum += __shfl_xor(psum, off, 64);
            l_r[r] = l_r[r] * alpha + psum;
            m_r[r] = mnew;
            #pragma unroll
            for (int t = 0; t < 4; ++t) o_acc[t][r] *= alpha;
        }

        // ---- P (C-layout) -> LDS -> A-fragment layout for PV ----
        #pragma unroll
        for (int n = 0; n < 2; ++n) {
            #pragma unroll
            for (int r = 0; r < 4; ++r)
                p_lds[wave][lhi * 4 + r][n * 16 + l16] = (bf16_t)p[n][r];
        }
        __syncthreads();

        bf16x8 pa;   // A-layout: row = l16 (q), k = lhi*8 + j (key within tile)
        #pragma unroll
        for (int j = 0; j < 8; ++j)
            pa[j] = p_lds[wave][l16][lhi * 8 + j];
        #pragma unroll
        for (int t = 0; t < 4; ++t) {
            bf16x8 vbf;  // B-layout: lane holds col t*16+l16 (d), k-dim = lhi*8+j (key)
            #pragma unroll
            for (int j = 0; j < 8; ++j)
                vbf[j] = v_lds[lhi * 8 + j][t * 16 + l16];
            o_acc[t] = __builtin_amdgcn_mfma_f32_16x16x32_bf16(pa, vbf, o_acc[t], 0, 0, 0);
        }
    }

    // ---- epilogue: divide by l, store fp32 ----
    float* op = out + (((size_t)b * Q_ + qt * 64 + wave * 16) * H_ + h) * D_;
    #pragma unroll
    for (int r = 0; r < 4; ++r) {
        const int   row = lhi * 4 + r;
        const float inv = 1.f / l_r[r];
        #pragma unroll
        for (int t = 0; t < 4; ++t)
            op[(size_t)row * (H_ * D_) + t * 16 + l16] = o_acc[t][r] * inv;
    }
}

extern "C" void kernel_launch(void* const* d_in, const int* in_sizes, int n_in,
                              void* d_out, int out_size, void* d_ws, size_t ws_size,
                              hipStream_t stream) {
    const float* qs = (const float*)d_in[0];
    const float* ks = (const float*)d_in[1];
    const float* vs = (const float*)d_in[2];
    const int*   vl = (const int*)d_in[3];
    float*       out = (float*)d_out;
    dim3 grid(Q_ / 64, H_, B_);
    attn_fwd_kernel<<<grid, 256, 0, stream>>>(qs, ks, vs, vl, out);
}

// Round 2
// 83.279 us; speedup vs baseline: 1.3633x; 1.3633x over previous
//
#include <hip/hip_runtime.h>

#define B_ 2
#define Q_ 2048
#define K_ 2048
#define H_ 16
#define D_ 64

typedef __bf16 bf16_t;
typedef __attribute__((ext_vector_type(8))) __bf16 bf16x8;
typedef __attribute__((ext_vector_type(4))) __bf16 bf16x4;
typedef __attribute__((ext_vector_type(4))) float f32x4;

// Swizzled byte offset for a [64][64] bf16 tile (row stride 128 B).
// XOR bits 4-6 with row&7: bijective (mask depends only on byte bits >=7),
// keeps 16B granules intact, spreads a column read across 8 bank slots.
__device__ __forceinline__ int swz(int row, int colByte) {
    return (row * 128 + colByte) ^ ((row & 7) << 4);
}

__global__ __launch_bounds__(256) void attn_fwd_kernel(
    const float* __restrict__ qs, const float* __restrict__ ks,
    const float* __restrict__ vs, const int* __restrict__ valid_lens,
    float* __restrict__ out)
{
    const int qt   = blockIdx.x;   // q-tile of 64 rows
    const int h    = blockIdx.y;
    const int b    = blockIdx.z;
    const int tid  = threadIdx.x;
    const int wave = tid >> 6;     // 0..3, each owns 16 q rows
    const int lane = tid & 63;
    const int l16  = lane & 15;
    const int lhi  = lane >> 4;    // 0..3

    const int valid  = valid_lens[b];
    const int ntiles = (valid + 63) >> 6;   // tiles fully past valid contribute exactly 0

    __shared__ bf16_t k_lds[64 * 64];   // [key][d], swizzled
    __shared__ bf16_t v_lds[64 * 64];   // [d][key] (transposed), swizzled
    __shared__ bf16_t p_buf[4][16 * 64]; // per-wave P tile [q][key], swizzled
    char* const kbase = (char*)k_lds;
    char* const vbase = (char*)v_lds;
    char* const pbase = (char*)&p_buf[wave][0];

    // ---- Q fragments (A-layout: lane = row l16, k-dim d = dh*32+lhi*8+j), scale folded ----
    const int    qrow = qt * 64 + wave * 16 + l16;
    const float* qp   = qs + (((size_t)b * Q_ + qrow) * H_ + h) * D_;
    bf16x8 a_q[2];
    #pragma unroll
    for (int dh = 0; dh < 2; ++dh) {
        const f32x4* q4 = (const f32x4*)(qp + dh * 32 + lhi * 8);
        f32x4 lo = q4[0], hi = q4[1];
        #pragma unroll
        for (int j = 0; j < 4; ++j) {
            a_q[dh][j]     = (bf16_t)(lo[j] * 0.125f);
            a_q[dh][4 + j] = (bf16_t)(hi[j] * 0.125f);
        }
    }

    f32x4 o_acc[4];
    #pragma unroll
    for (int t = 0; t < 4; ++t) o_acc[t] = (f32x4){0.f, 0.f, 0.f, 0.f};
    float m_r[4], l_r[4];
    #pragma unroll
    for (int r = 0; r < 4; ++r) { m_r[r] = -1e30f; l_r[r] = 0.f; }

    const float* kb = ks + ((size_t)b * K_ * H_ + h) * D_;   // + key*H_*D_
    const float* vg = vs + ((size_t)b * K_ * H_ + h) * D_;

    // staging maps
    const int krow = tid >> 2;          // 0..63 (key)
    const int kcol = (tid & 3) * 16;    // float col base
    const int vr   = (tid & 15) * 4;    // key base (4 rows)
    const int vc   = (tid >> 4) * 4;    // d base (4 cols)

    for (int kt = 0; kt < ntiles; ++kt) {
        __syncthreads();   // protect K/V LDS from previous iteration's readers
        // ---- stage K: row-major, vectorized, swizzled ----
        {
            const float* src = kb + (size_t)(kt * 64 + krow) * (H_ * D_) + kcol;
            f32x4 f0 = ((const f32x4*)src)[0], f1 = ((const f32x4*)src)[1];
            f32x4 f2 = ((const f32x4*)src)[2], f3 = ((const f32x4*)src)[3];
            bf16x8 lo, hi;
            #pragma unroll
            for (int j = 0; j < 4; ++j) {
                lo[j] = (bf16_t)f0[j]; lo[4 + j] = (bf16_t)f1[j];
                hi[j] = (bf16_t)f2[j]; hi[4 + j] = (bf16_t)f3[j];
            }
            *(bf16x8*)(kbase + swz(krow, kcol * 2))      = lo;
            *(bf16x8*)(kbase + swz(krow, kcol * 2 + 16)) = hi;
        }
        // ---- stage V transposed: 4x4 register transpose, b64 writes, swizzled ----
        {
            f32x4 r4[4];
            #pragma unroll
            for (int i = 0; i < 4; ++i)
                r4[i] = *(const f32x4*)(vg + (size_t)(kt * 64 + vr + i) * (H_ * D_) + vc);
            #pragma unroll
            for (int j = 0; j < 4; ++j) {
                bf16x4 w;
                w[0] = (bf16_t)r4[0][j]; w[1] = (bf16_t)r4[1][j];
                w[2] = (bf16_t)r4[2][j]; w[3] = (bf16_t)r4[3][j];
                *(bf16x4*)(vbase + swz(vc + j, vr * 2)) = w;
            }
        }
        __syncthreads();

        // ---- S = (Q*scale) K^T : four 16-key n-tiles, d-dim 64 in 2 halves ----
        f32x4 s[4];
        #pragma unroll
        for (int n = 0; n < 4; ++n) s[n] = (f32x4){0.f, 0.f, 0.f, 0.f};
        #pragma unroll
        for (int n = 0; n < 4; ++n) {
            #pragma unroll
            for (int dh = 0; dh < 2; ++dh) {
                bf16x8 bk = *(const bf16x8*)(kbase + swz(n * 16 + l16, dh * 64 + lhi * 16));
                s[n] = __builtin_amdgcn_mfma_f32_16x16x32_bf16(a_q[dh], bk, s[n], 0, 0, 0);
            }
        }

        // ---- mask (key padding) ----
        float p[4][4];
        #pragma unroll
        for (int n = 0; n < 4; ++n) {
            const bool ok = (kt * 64 + n * 16 + l16) < valid;
            #pragma unroll
            for (int r = 0; r < 4; ++r)
                p[n][r] = ok ? s[n][r] : -1e30f;
        }

        // ---- online softmax: rows live on 16-lane groups (row = lhi*4 + r) ----
        #pragma unroll
        for (int r = 0; r < 4; ++r) {
            float rm = fmaxf(fmaxf(p[0][r], p[1][r]), fmaxf(p[2][r], p[3][r]));
            #pragma unroll
            for (int off = 1; off < 16; off <<= 1)
                rm = fmaxf(rm, __shfl_xor(rm, off, 64));
            const float mnew  = fmaxf(m_r[r], rm);
            const float alpha = __expf(m_r[r] - mnew);
            float psum = 0.f;
            #pragma unroll
            for (int n = 0; n < 4; ++n) {
                const float e = __expf(p[n][r] - mnew);
                p[n][r] = e;
                psum += e;
            }
            #pragma unroll
            for (int off = 1; off < 16; off <<= 1)
                psum += __shfl_xor(psum, off, 64);
            l_r[r] = l_r[r] * alpha + psum;
            m_r[r] = mnew;
            #pragma unroll
            for (int t = 0; t < 4; ++t) o_acc[t][r] *= alpha;
        }

        // ---- P (C-layout) -> wave-private LDS (swizzled) -> A-fragments; no barrier needed ----
        #pragma unroll
        for (int n = 0; n < 4; ++n) {
            #pragma unroll
            for (int r = 0; r < 4; ++r)
                *(bf16_t*)(pbase + swz(lhi * 4 + r, (n * 16 + l16) * 2)) = (bf16_t)p[n][r];
        }
        bf16x8 pa[2];
        #pragma unroll
        for (int kk = 0; kk < 2; ++kk)
            pa[kk] = *(const bf16x8*)(pbase + swz(l16, kk * 64 + lhi * 16));

        // ---- PV: O += P * V  (B-fragments from transposed V, b128 swizzled reads) ----
        #pragma unroll
        for (int t = 0; t < 4; ++t) {
            #pragma unroll
            for (int kk = 0; kk < 2; ++kk) {
                bf16x8 vb = *(const bf16x8*)(vbase + swz(t * 16 + l16, kk * 64 + lhi * 16));
                o_acc[t] = __builtin_amdgcn_mfma_f32_16x16x32_bf16(pa[kk], vb, o_acc[t], 0, 0, 0);
            }
        }
    }

    // ---- epilogue: divide by l, store fp32 ----
    float* op = out + (((size_t)b * Q_ + qt * 64 + wave * 16) * H_ + h) * D_;
    #pragma unroll
    for (int r = 0; r < 4; ++r) {
        const int   row = lhi * 4 + r;
        const float inv = 1.f / l_r[r];
        #pragma unroll
        for (int t = 0; t < 4; ++t)
            op[(size_t)row * (H_ * D_) + t * 16 + l16] = o_acc[t][r] * inv;
    }
}

extern "C" void kernel_launch(void* const* d_in, const int* in_sizes, int n_in,
                              void* d_out, int out_size, void* d_ws, size_t ws_size,
                              hipStream_t stream) {
    const float* qs = (const float*)d_in[0];
    const float* ks = (const float*)d_in[1];
    const float* vs = (const float*)d_in[2];
    const int*   vl = (const int*)d_in[3];
    float*       out = (float*)d_out;
    dim3 grid(Q_ / 64, H_, B_);
    attn_fwd_kernel<<<grid, 256, 0, stream>>>(qs, ks, vs, vl, out);
}

// Round 3
// 75.684 us; speedup vs baseline: 1.5001x; 1.1004x over previous
//
#include <hip/hip_runtime.h>

#define B_ 2
#define Q_ 2048
#define K_ 2048
#define H_ 16
#define D_ 64
#define HD_ (H_ * D_)

typedef __bf16 bf16_t;
typedef __attribute__((ext_vector_type(8))) __bf16 bf16x8;
typedef __attribute__((ext_vector_type(4))) __bf16 bf16x4;
typedef __attribute__((ext_vector_type(4))) float f32x4;

// Swizzled byte offset for a [N][64] bf16 tile (row stride 128 B).
// XOR bits 4-6 with row&7: bijective, keeps 16B granules, kills bank conflicts.
__device__ __forceinline__ int swz(int row, int colByte) {
    return (row * 128 + colByte) ^ ((row & 7) << 4);
}

__global__ __launch_bounds__(256) void attn_fwd_kernel(
    const float* __restrict__ qs, const float* __restrict__ ks,
    const float* __restrict__ vs, const int* __restrict__ valid_lens,
    float* __restrict__ out)
{
    const int qt   = blockIdx.x;   // 128-row q tile
    const int h    = blockIdx.y;
    const int b    = blockIdx.z;
    const int tid  = threadIdx.x;
    const int wave = tid >> 6;     // 0..3, each owns 32 q rows (two 16-row frags)
    const int lane = tid & 63;
    const int l16  = lane & 15;
    const int lhi  = lane >> 4;    // 0..3

    const int valid  = valid_lens[b];
    const int ntiles = (valid + 63) >> 6;   // tiles fully past valid contribute exactly 0

    __shared__ bf16_t k_lds[2][64 * 64];    // [buf][key][d], swizzled
    __shared__ bf16_t v_lds[2][64 * 64];    // [buf][d][key] transposed, swizzled
    __shared__ bf16_t p_buf[4][32 * 64];    // per-wave P tile [q][key], swizzled
    char* const pbase = (char*)&p_buf[wave][0];

    // ---- Q fragments (A-layout: lane = row l16, k-dim d = dh*32+lhi*8+j), scale folded ----
    bf16x8 a_q[2][2];
    #pragma unroll
    for (int f = 0; f < 2; ++f) {
        const int    qrow = qt * 128 + wave * 32 + f * 16 + l16;
        const float* qp   = qs + (((size_t)b * Q_ + qrow) * H_ + h) * D_;
        #pragma unroll
        for (int dh = 0; dh < 2; ++dh) {
            const f32x4* q4 = (const f32x4*)(qp + dh * 32 + lhi * 8);
            f32x4 lo = q4[0], hi = q4[1];
            #pragma unroll
            for (int j = 0; j < 4; ++j) {
                a_q[f][dh][j]     = (bf16_t)(lo[j] * 0.125f);
                a_q[f][dh][4 + j] = (bf16_t)(hi[j] * 0.125f);
            }
        }
    }

    f32x4 o_acc[2][4];
    float m_r[2][4], l_r[2][4];
    #pragma unroll
    for (int f = 0; f < 2; ++f) {
        #pragma unroll
        for (int t = 0; t < 4; ++t) o_acc[f][t] = (f32x4){0.f, 0.f, 0.f, 0.f};
        #pragma unroll
        for (int r = 0; r < 4; ++r) { m_r[f][r] = -1e30f; l_r[f][r] = 0.f; }
    }

    const float* kb = ks + ((size_t)b * K_ * H_ + h) * D_;
    const float* vg = vs + ((size_t)b * K_ * H_ + h) * D_;

    // staging maps
    const int krow  = tid >> 2;          // 0..63 (key)
    const int kcolf = (tid & 3) * 16;    // float col base
    const int vr    = (tid & 15) * 4;    // key base (4 rows)
    const int vc    = (tid >> 4) * 4;    // d base (4 cols)

    f32x4 kreg[4], vreg[4];   // in-flight next tile

    auto issue_loads = [&](int kt) {
        const float* ksrc = kb + (size_t)(kt * 64 + krow) * HD_ + kcolf;
        #pragma unroll
        for (int i = 0; i < 4; ++i) kreg[i] = ((const f32x4*)ksrc)[i];
        #pragma unroll
        for (int i = 0; i < 4; ++i)
            vreg[i] = *(const f32x4*)(vg + (size_t)(kt * 64 + vr + i) * HD_ + vc);
    };

    auto write_tile = [&](int bi) {
        char* kdst = (char*)&k_lds[bi][0];
        char* vdst = (char*)&v_lds[bi][0];
        bf16x8 lo, hi;
        #pragma unroll
        for (int j = 0; j < 4; ++j) {
            lo[j] = (bf16_t)kreg[0][j]; lo[4 + j] = (bf16_t)kreg[1][j];
            hi[j] = (bf16_t)kreg[2][j]; hi[4 + j] = (bf16_t)kreg[3][j];
        }
        *(bf16x8*)(kdst + swz(krow, kcolf * 2))      = lo;
        *(bf16x8*)(kdst + swz(krow, kcolf * 2 + 16)) = hi;
        #pragma unroll
        for (int j = 0; j < 4; ++j) {
            bf16x4 w;
            w[0] = (bf16_t)vreg[0][j]; w[1] = (bf16_t)vreg[1][j];
            w[2] = (bf16_t)vreg[2][j]; w[3] = (bf16_t)vreg[3][j];
            *(bf16x4*)(vdst + swz(vc + j, vr * 2)) = w;
        }
    };

    // prologue: tile 0 straight to LDS
    issue_loads(0);
    write_tile(0);
    int cur = 0;

    for (int kt = 0; kt < ntiles; ++kt) {
        const bool more = (kt + 1 < ntiles);
        if (more) issue_loads(kt + 1);          // in flight across the whole compute phase
        __syncthreads();                        // buf[cur] writes visible

        char* const kbase = (char*)&k_lds[cur][0];
        char* const vbase = (char*)&v_lds[cur][0];

        // ---- S = (Q*scale) K^T : shared K-frag reads feed both q sub-tiles ----
        f32x4 s[2][4];
        #pragma unroll
        for (int f = 0; f < 2; ++f)
            #pragma unroll
            for (int n = 0; n < 4; ++n) s[f][n] = (f32x4){0.f, 0.f, 0.f, 0.f};
        #pragma unroll
        for (int n = 0; n < 4; ++n) {
            #pragma unroll
            for (int dh = 0; dh < 2; ++dh) {
                bf16x8 bk = *(const bf16x8*)(kbase + swz(n * 16 + l16, dh * 64 + lhi * 16));
                s[0][n] = __builtin_amdgcn_mfma_f32_16x16x32_bf16(a_q[0][dh], bk, s[0][n], 0, 0, 0);
                s[1][n] = __builtin_amdgcn_mfma_f32_16x16x32_bf16(a_q[1][dh], bk, s[1][n], 0, 0, 0);
            }
        }

        // ---- mask only on the boundary tile (uniform branch) ----
        if (kt * 64 + 64 > valid) {
            #pragma unroll
            for (int n = 0; n < 4; ++n) {
                const bool ok = (kt * 64 + n * 16 + l16) < valid;
                #pragma unroll
                for (int f = 0; f < 2; ++f)
                    #pragma unroll
                    for (int r = 0; r < 4; ++r)
                        if (!ok) s[f][n][r] = -1e30f;
            }
        }

        // ---- online softmax (rows on 16-lane groups) + P to wave-private LDS ----
        #pragma unroll
        for (int f = 0; f < 2; ++f) {
            #pragma unroll
            for (int r = 0; r < 4; ++r) {
                float rm = fmaxf(fmaxf(s[f][0][r], s[f][1][r]), fmaxf(s[f][2][r], s[f][3][r]));
                #pragma unroll
                for (int off = 1; off < 16; off <<= 1)
                    rm = fmaxf(rm, __shfl_xor(rm, off, 64));
                const float mnew  = fmaxf(m_r[f][r], rm);
                const float alpha = __expf(m_r[f][r] - mnew);
                float e[4], psum = 0.f;
                #pragma unroll
                for (int n = 0; n < 4; ++n) {
                    e[n] = __expf(s[f][n][r] - mnew);
                    psum += e[n];
                }
                #pragma unroll
                for (int off = 1; off < 16; off <<= 1)
                    psum += __shfl_xor(psum, off, 64);
                l_r[f][r] = l_r[f][r] * alpha + psum;
                m_r[f][r] = mnew;
                #pragma unroll
                for (int t = 0; t < 4; ++t) o_acc[f][t][r] *= alpha;
                #pragma unroll
                for (int n = 0; n < 4; ++n)
                    *(bf16_t*)(pbase + swz(f * 16 + lhi * 4 + r, (n * 16 + l16) * 2)) = (bf16_t)e[n];
            }
        }

        bf16x8 pa[2][2];
        #pragma unroll
        for (int f = 0; f < 2; ++f)
            #pragma unroll
            for (int kk = 0; kk < 2; ++kk)
                pa[f][kk] = *(const bf16x8*)(pbase + swz(f * 16 + l16, kk * 64 + lhi * 16));

        // ---- PV: shared V-frag reads feed both q sub-tiles ----
        #pragma unroll
        for (int t = 0; t < 4; ++t) {
            #pragma unroll
            for (int kk = 0; kk < 2; ++kk) {
                bf16x8 vb = *(const bf16x8*)(vbase + swz(t * 16 + l16, kk * 64 + lhi * 16));
                o_acc[0][t] = __builtin_amdgcn_mfma_f32_16x16x32_bf16(pa[0][kk], vb, o_acc[0][t], 0, 0, 0);
                o_acc[1][t] = __builtin_amdgcn_mfma_f32_16x16x32_bf16(pa[1][kk], vb, o_acc[1][t], 0, 0, 0);
            }
        }

        __syncthreads();                        // everyone done reading buf[cur^1] long ago; done with cur
        if (more) write_tile(cur ^ 1);          // regs -> LDS for next tile
        cur ^= 1;
    }

    // ---- epilogue: divide by l, store fp32 ----
    #pragma unroll
    for (int f = 0; f < 2; ++f) {
        float* op = out + (((size_t)b * Q_ + qt * 128 + wave * 32 + f * 16) * H_ + h) * D_;
        #pragma unroll
        for (int r = 0; r < 4; ++r) {
            const int   row = lhi * 4 + r;
            const float inv = 1.f / l_r[f][r];
            #pragma unroll
            for (int t = 0; t < 4; ++t)
                op[(size_t)row * HD_ + t * 16 + l16] = o_acc[f][t][r] * inv;
        }
    }
}

extern "C" void kernel_launch(void* const* d_in, const int* in_sizes, int n_in,
                              void* d_out, int out_size, void* d_ws, size_t ws_size,
                              hipStream_t stream) {
    const float* qs = (const float*)d_in[0];
    const float* ks = (const float*)d_in[1];
    const float* vs = (const float*)d_in[2];
    const int*   vl = (const int*)d_in[3];
    float*       out = (float*)d_out;
    dim3 grid(Q_ / 128, H_, B_);
    attn_fwd_kernel<<<grid, 256, 0, stream>>>(qs, ks, vs, vl, out);
}